// Round 11
// baseline (416.171 us; speedup 1.0000x reference)
//
#include <hip/hip_runtime.h>
#include <stdint.h>

#define T_ 65536
#define HW_ 16384
#define SCALE_F 0.08838834764831845f
#define EPS_ 1e-4f

typedef unsigned short u16;
typedef unsigned int u32;
typedef __attribute__((ext_vector_type(4))) float f32x4;
typedef __attribute__((ext_vector_type(8))) __bf16 bf16x8v;

union frag_u { u16 h[8]; bf16x8v v; uint4 q4; };

__device__ __forceinline__ float bf2f(u16 h) {
    union { u32 u; float f; } x; x.u = ((u32)h) << 16; return x.f;
}
__device__ __forceinline__ u16 f2bf(float f) {
    union { u32 u; float f; } x; x.f = f;
    u32 u = x.u;
    return (u16)((u + 0x7FFFu + ((u >> 16) & 1u)) >> 16);
}
__device__ __forceinline__ f32x4 mfma_b(bf16x8v a, bf16x8v b, f32x4 c) {
    return __builtin_amdgcn_mfma_f32_16x16x32_bf16(a, b, c, 0, 0, 0);
}
// async global->LDS 16B: lds dest = wave-uniform base + lane*16
__device__ __forceinline__ void gl_lds16(const u16* g, u16* l) {
    __builtin_amdgcn_global_load_lds(
        (const __attribute__((address_space(1))) void*)g,
        (__attribute__((address_space(3))) void*)l, 16, 0, 0);
}

// window-major token u -> global token t (br0: vertical strips 128x4)
__device__ __forceinline__ int u2t(int u, int br) {
    if (br == 1) return u;
    int b = u >> 14, rr = u & 16383;
    int s = rr >> 9, rem = rr & 511;
    int y = rem >> 2, xl = rem & 3;
    return (b << 14) + (y << 7) + (s << 2) + xl;
}
// global token t -> br0 window-major u
__device__ __forceinline__ int t2u0(int t) {
    int b = t >> 14, rr = t & 16383;
    int y = rr >> 7, x = rr & 127;
    return (b << 14) + ((x >> 2) << 9) + (y << 2) + (x & 3);
}

__global__ void sentinel_kernel(float* out, float code) {
    if (blockIdx.x == 0 && threadIdx.x == 0) out[0] = code;
}

// ---------------- K0: weight pre-convert ----------------
// blocks [0,64): w_qkv -> wtf, fragment-ordered bf16:
//   chunk id = ((((my*2+br)*2+wm)*8+ks)*4+i)*64 + lane  (16B each)
//   content: w_qkv[k][col], k = ks*32+(lane>>4)*8+e, col = my*256+br*128+wm*64+i*16+(lane&15)
// blocks [64,96): pw -> pwc bf16, k-permutation baked in
__global__ __launch_bounds__(256) void wconv_kernel(const float* __restrict__ w,
        const float* __restrict__ pw, u16* __restrict__ wtf, u16* __restrict__ pwc) {
    int bid = blockIdx.x;
    int tid = threadIdx.x;
    if (bid < 64) {
        for (int it = 0; it < 3; ++it) {
            int id = (bid * 3 + it) * 256 + tid;   // 49152 chunks
            int lane = id & 63;
            int i  = (id >> 6) & 3;
            int ks = (id >> 8) & 7;
            int wm = (id >> 11) & 1;
            int br = (id >> 12) & 1;
            int my = id >> 13;
            int col = my * 256 + br * 128 + wm * 64 + i * 16 + (lane & 15);
            int k0 = ks * 32 + ((lane >> 4) & 3) * 8;
            u16 tmp[8] __attribute__((aligned(16)));
            #pragma unroll
            for (int e = 0; e < 8; ++e)
                tmp[e] = f2bf(w[(size_t)(k0 + e) * 768 + col]);
            *(uint4*)&wtf[(size_t)id * 8] = *(const uint4*)tmp;
        }
    } else {
        int base = (bid - 64) * 2048;
        for (int i = 0; i < 8; ++i) {
            int e = base + i * 256 + tid;
            int m = e >> 8, ks = e & 255;
            int c = (ks < 128) ? (2 * (ks & 63) + (ks >> 6))
                               : (128 + 2 * ((ks - 128) & 63) + ((ks - 128) >> 6));
            pwc[e] = f2bf(pw[(size_t)m * 256 + c]);
        }
    }
}

// ---------------- K1: LayerNorm over C, burst-contiguous reads ----------------
__global__ __launch_bounds__(512, 2) void ln_kernel(const float* __restrict__ x,
        const float* __restrict__ g, const float* __restrict__ bta, u16* __restrict__ xn) {
    __shared__ float reds[8][260];
    __shared__ float redss[8][260];
    __shared__ float mus[256];
    __shared__ float rstds[256];
    int tid = threadIdx.x, lane = tid & 63, w = tid >> 6;
    int w32 = w * 32;
    int tok0 = blockIdx.x * 256 + lane * 4;
    int b = tok0 >> 14, hw = tok0 & 16383;
    const float* xb = x + (size_t)b * 256 * HW_ + hw;
    float4 v[32];
    #pragma unroll
    for (int j = 0; j < 32; ++j)
        v[j] = *(const float4*)(xb + (size_t)(w32 + j) * HW_);
    float s0 = 0.f, s1 = 0.f, s2 = 0.f, s3 = 0.f;
    float q0 = 0.f, q1 = 0.f, q2 = 0.f, q3 = 0.f;
    #pragma unroll
    for (int j = 0; j < 32; ++j) {
        s0 += v[j].x; q0 += v[j].x * v[j].x;
        s1 += v[j].y; q1 += v[j].y * v[j].y;
        s2 += v[j].z; q2 += v[j].z * v[j].z;
        s3 += v[j].w; q3 += v[j].w * v[j].w;
    }
    *(float4*)&reds[w][lane * 4]  = make_float4(s0, s1, s2, s3);
    *(float4*)&redss[w][lane * 4] = make_float4(q0, q1, q2, q3);
    __syncthreads();
    if (tid < 256) {
        float S = 0.f, SS = 0.f;
        #pragma unroll
        for (int p = 0; p < 8; ++p) { S += reds[p][tid]; SS += redss[p][tid]; }
        float mu = S * (1.f / 256.f);
        float var = SS * (1.f / 256.f) - mu * mu;
        mus[tid] = mu;
        rstds[tid] = rsqrtf(var + EPS_);
    }
    __syncthreads();
    float4 mu4 = *(const float4*)&mus[lane * 4];
    float4 rs4 = *(const float4*)&rstds[lane * 4];
    float mk[4] = {mu4.x, mu4.y, mu4.z, mu4.w};
    float rk[4] = {rs4.x, rs4.y, rs4.z, rs4.w};
    #pragma unroll
    for (int k = 0; k < 4; ++k) {
        u16 tmp[32] __attribute__((aligned(16)));
        #pragma unroll
        for (int j = 0; j < 32; ++j) {
            int c = w32 + j;
            float xv = (k == 0) ? v[j].x : (k == 1) ? v[j].y : (k == 2) ? v[j].z : v[j].w;
            tmp[j] = f2bf((xv - mk[k]) * rk[k] * g[c] + bta[c]);
        }
        u16* o = xn + (size_t)(tok0 + k) * 256 + w32;
        *(uint4*)(o)      = *(const uint4*)&tmp[0];
        *(uint4*)(o + 8)  = *(const uint4*)&tmp[8];
        *(uint4*)(o + 16) = *(const uint4*)&tmp[16];
        *(uint4*)(o + 24) = *(const uint4*)&tmp[24];
    }
}

// ---------------- K2: merged Q/K/V GEMM ----------------
// Block stages full-K B (128 tokens x 256k = 64KB) ONCE via gload_lds in 1KB/wave bursts,
// XOR-swizzled (chunk ^= row&7) via pre-swizzled global source (linear LDS dest).
// Then 3 my-phases (Q,K,V) with A-frags loaded coalesced from L2-resident wtf.
__global__ __launch_bounds__(256) void qkv_gemm(const u16* __restrict__ wtf,
        const u16* __restrict__ xn, u16* __restrict__ qkt, u16* __restrict__ vpl, int br) {
    __shared__ __align__(16) u16 b_lds[128 * 256];   // 64 KB
    int n0 = blockIdx.x * 128;
    int tid = threadIdx.x;
    int lane = tid & 63, wid = tid >> 6;
    int wm = wid >> 1, wn = wid & 1;
    int l15 = lane & 15, quad = lane >> 4;
    // ---- stage B: 16 rounds, wave covers 2 full rows (1KB contiguous global)
    {
        int rowoff = lane >> 5;          // 0/1 within wave
        int c_lds = lane & 31;           // 16B chunk slot within row
        for (int r = 0; r < 16; ++r) {
            int row = r * 8 + wid * 2 + rowoff;
            int t = u2t(n0 + row, br);
            int cg = c_lds ^ (row & 7);  // inverse-swizzled source chunk
            const u16* gsrc = xn + (size_t)t * 256 + cg * 8;
            u16* ldst = &b_lds[(r * 8 + wid * 2) * 256];   // wave-uniform base
            gl_lds16(gsrc, ldst);
        }
    }
    __syncthreads();   // vmcnt(0) drain: staged B visible
    #pragma unroll 1
    for (int my = 0; my < 3; ++my) {
        const u16* abase = wtf + (size_t)(((my * 2 + br) * 2 + wm) * 8) * 4 * 64 * 8;
        f32x4 acc[4][4] = {};
        #pragma unroll
        for (int ks = 0; ks < 8; ++ks) {
            frag_u af[4];
            bf16x8v bf[4];
            #pragma unroll
            for (int i = 0; i < 4; ++i)
                af[i].q4 = *(const uint4*)&abase[(size_t)(ks * 4 + i) * 512 + lane * 8];
            #pragma unroll
            for (int i = 0; i < 4; ++i) {
                int rowb = wn * 64 + i * 16 + l15;
                int cl2 = (ks * 4 + quad) ^ (rowb & 7);   // swizzled read
                bf[i] = *(const bf16x8v*)&b_lds[rowb * 256 + cl2 * 8];
            }
            #pragma unroll
            for (int i = 0; i < 4; ++i)
                #pragma unroll
                for (int j = 0; j < 4; ++j)
                    acc[i][j] = mfma_b(af[i].v, bf[j], acc[i][j]);
        }
        if (my < 2) {
            int cb2 = my * 128;
            #pragma unroll
            for (int i = 0; i < 4; ++i) {
                #pragma unroll
                for (int r = 0; r < 4; ++r) {
                    int cl = wm * 64 + i * 16 + quad * 4 + r;
                    int col = cb2 + ((cl & 1) << 6) + (cl >> 1);
                    #pragma unroll
                    for (int j = 0; j < 4; ++j) {
                        int u = n0 + wn * 64 + j * 16 + l15;
                        qkt[(size_t)u * 256 + col] = f2bf(acc[i][j][r]);
                    }
                }
            }
        } else {
            #pragma unroll
            for (int i = 0; i < 4; ++i) {
                int pbase = wm * 64 + i * 16 + quad * 4;
                #pragma unroll
                for (int j = 0; j < 4; ++j) {
                    int u = n0 + wn * 64 + j * 16 + l15;
                    #pragma unroll
                    for (int r = 0; r < 4; ++r)
                        vpl[(size_t)(pbase + r) * T_ + u] = f2bf(acc[i][j][r]);
                }
            }
        }
    }
}

// ---------------- K3: attention, flash-style online softmax; 70KB LDS -> 2 blocks/CU ----
__global__ __launch_bounds__(512, 4) void attn_kernel(const u16* __restrict__ qkt,
        const u16* __restrict__ vpl, u16* __restrict__ xcb, int stride) {
    __shared__ __align__(16) u16 k_area[2][128 * 72];   // 36864 B
    __shared__ __align__(16) u16 v_lds[2][64 * 136];    // 34816 B
    int bid = blockIdx.x;
    int id2 = (bid & 7) * 128 + (bid >> 3);   // XCD swizzle: one window's 8 blocks share an XCD
    int window = id2 >> 3, h = (id2 >> 2) & 1, qq = id2 & 3;
    int wbase = window * 512;
    int tid = threadIdx.x, lane = tid & 63, wid = tid >> 6;
    int l15 = lane & 15, quad = lane >> 4;

    // Q A-frags (token-major rows, de-interleaved: cols h*64 + cd)
    frag_u af[2];
    {
        size_t qrow = (size_t)(wbase + qq * 128 + wid * 16 + l15) * 256 + h * 64 + quad * 8;
        af[0].q4 = *(const uint4*)&qkt[qrow];
        af[1].q4 = *(const uint4*)&qkt[qrow + 32];
    }
    // stage K chunk 0 + V chunk 0
    for (int idx = tid; idx < 1024; idx += 512) {
        int tok = idx >> 3, c8 = (idx & 7) * 8;
        *(uint4*)&k_area[0][tok * 72 + c8] =
            *(const uint4*)&qkt[(size_t)(wbase + tok) * 256 + 128 + h * 64 + c8];
    }
    for (int idx = tid; idx < 1024; idx += 512) {
        int cd = idx >> 4, k8 = (idx & 15) * 8;
        *(uint4*)&v_lds[0][cd * 136 + k8] =
            *(const uint4*)&vpl[(size_t)(2 * cd + h) * T_ + wbase + k8];
    }
    __syncthreads();

    float m[4] = {-1e30f, -1e30f, -1e30f, -1e30f};
    float l[4] = {0.f, 0.f, 0.f, 0.f};   // lane-partial; reduced once at the end
    f32x4 acc_o[4] = {};
    for (int ch = 0; ch < 4; ++ch) {
        int cur = ch & 1, nxt = cur ^ 1;
        if (ch < 3) {   // prefetch next K/V chunk into the other buffers
            for (int idx = tid; idx < 1024; idx += 512) {
                int tok = idx >> 3, c8 = (idx & 7) * 8;
                *(uint4*)&k_area[nxt][tok * 72 + c8] =
                    *(const uint4*)&qkt[(size_t)(wbase + (ch + 1) * 128 + tok) * 256 + 128 + h * 64 + c8];
            }
            for (int idx = tid; idx < 1024; idx += 512) {
                int cd = idx >> 4, k8 = (idx & 15) * 8;
                *(uint4*)&v_lds[nxt][cd * 136 + k8] =
                    *(const uint4*)&vpl[(size_t)(2 * cd + h) * T_ + wbase + (ch + 1) * 128 + k8];
            }
        }
        // ---- S chunk = Q.K^T (lane: q-row = quad*4+r, k-col = kt*16+l15)
        f32x4 s[8];
        #pragma unroll
        for (int kt = 0; kt < 8; ++kt) {
            f32x4 z = {0.f, 0.f, 0.f, 0.f};
            bf16x8v b0 = *(const bf16x8v*)&k_area[cur][(kt * 16 + l15) * 72 + quad * 8];
            bf16x8v b1 = *(const bf16x8v*)&k_area[cur][(kt * 16 + l15) * 72 + 32 + quad * 8];
            z = mfma_b(af[0].v, b0, z);
            z = mfma_b(af[1].v, b1, z);
            s[kt] = z;
        }
        // ---- online softmax update
        float cmx[4] = {-1e30f, -1e30f, -1e30f, -1e30f};
        #pragma unroll
        for (int kt = 0; kt < 8; ++kt)
            #pragma unroll
            for (int r = 0; r < 4; ++r) cmx[r] = fmaxf(cmx[r], s[kt][r]);
        #pragma unroll
        for (int d = 1; d < 16; d <<= 1)
            #pragma unroll
            for (int r = 0; r < 4; ++r) cmx[r] = fmaxf(cmx[r], __shfl_xor(cmx[r], d, 16));
        float alpha[4];
        #pragma unroll
        for (int r = 0; r < 4; ++r) {
            float mn = fmaxf(m[r], cmx[r]);
            alpha[r] = __expf((m[r] - mn) * SCALE_F);
            m[r] = mn;
        }
        float ps[4] = {0.f, 0.f, 0.f, 0.f};
        #pragma unroll
        for (int kt = 0; kt < 8; ++kt)
            #pragma unroll
            for (int r = 0; r < 4; ++r) {
                float p = __expf((s[kt][r] - m[r]) * SCALE_F);
                s[kt][r] = p;
                ps[r] += p;
            }
        #pragma unroll
        for (int r = 0; r < 4; ++r) l[r] = l[r] * alpha[r] + ps[r];
        #pragma unroll
        for (int cs = 0; cs < 4; ++cs)
            #pragma unroll
            for (int r = 0; r < 4; ++r) acc_o[cs][r] *= alpha[r];
        __syncthreads();   // all waves done reading k_area[cur] before P overlays it
        // ---- P.V for this chunk (P transposed via wave-private overlay on k_area[cur])
        u16* p_lds = &k_area[cur][wid * 1152];
        #pragma unroll
        for (int half = 0; half < 2; ++half) {
            #pragma unroll
            for (int kt4 = 0; kt4 < 4; ++kt4)
                #pragma unroll
                for (int rr = 0; rr < 4; ++rr)
                    p_lds[(quad * 4 + rr) * 72 + kt4 * 16 + l15] = f2bf(s[half * 4 + kt4][rr]);
            #pragma unroll
            for (int k32 = 0; k32 < 2; ++k32) {
                bf16x8v pa = *(const bf16x8v*)&p_lds[l15 * 72 + k32 * 32 + quad * 8];
                #pragma unroll
                for (int cs = 0; cs < 4; ++cs) {
                    bf16x8v vf = *(const bf16x8v*)&v_lds[cur]
                        [(cs * 16 + l15) * 136 + half * 64 + k32 * 32 + quad * 8];
                    acc_o[cs] = mfma_b(pa, vf, acc_o[cs]);
                }
            }
        }
        __syncthreads();   // prefetch landed; p_lds reads done before next iter's overwrite
    }
    // ---- final: reduce l across the 16-lane row group, normalize, store
    float linv[4];
    #pragma unroll
    for (int r = 0; r < 4; ++r) {
        float v = l[r];
        #pragma unroll
        for (int d = 1; d < 16; d <<= 1) v += __shfl_xor(v, d, 16);
        linv[r] = 1.f / v;
    }
    #pragma unroll
    for (int cs = 0; cs < 4; ++cs) {
        int col = h * 64 + cs * 16 + l15;
        #pragma unroll
        for (int r = 0; r < 4; ++r) {
            int u = wbase + qq * 128 + wid * 16 + quad * 4 + r;
            xcb[(size_t)u * stride + col] = f2bf(acc_o[cs][r] * linv[r]);
        }
    }
}

// ---------------- K3b: LePE depthwise 3x3, window-tiled with LDS transpose ----------------
__global__ __launch_bounds__(512) void lepe_kernel(const u16* __restrict__ vpl,
        const float* __restrict__ lw, const float* __restrict__ lb,
        u16* __restrict__ xcb, int stride, int br) {
    __shared__ __align__(16) u16 o_s[512 * 72];   // 73728 B, rows 16B-aligned
    int hh = blockIdx.x & 1, wdw = blockIdx.x >> 1;
    int wbase = wdw * 512;
    int tid = threadIdx.x;
    int xd = (br == 0) ? 4 : 128;   // y-step in u-space (window image: br0 128x4, br1 4x128)
    // ---- phase 1: conv; thread group g covers (cd, 8-token run)
    for (int i = 0; i < 8; ++i) {
        int g = i * 512 + tid;
        int cd = g >> 6, u0 = (g & 63) * 8;
        int cl = 2 * cd + hh;
        const u16* vp = vpl + (size_t)cl * T_ + wbase;
        const float* wp = lw + cl * 9;
        float bias = lb[cl];
        float acc[8];
        #pragma unroll
        for (int j = 0; j < 8; ++j) acc[j] = bias;
        #pragma unroll
        for (int r = -1; r <= 1; ++r) {
            int offA = u0 + r * xd;     // y-tap validity: tok+r*xd in [0,512)
            int offB = offA + 4;
            float m[8];
            if (offA >= 0 && offA <= 508) {
                uint2 va = *(const uint2*)&vp[offA];
                u16 ha[4]; *(uint2*)ha = va;
                #pragma unroll
                for (int j = 0; j < 4; ++j) m[j] = bf2f(ha[j]);
            } else { m[0] = m[1] = m[2] = m[3] = 0.f; }
            if (offB >= 0 && offB <= 508) {
                uint2 vb = *(const uint2*)&vp[offB];
                u16 hb[4]; *(uint2*)hb = vb;
                #pragma unroll
                for (int j = 0; j < 4; ++j) m[4 + j] = bf2f(hb[j]);
            } else { m[4] = m[5] = m[6] = m[7] = 0.f; }
            float le = 0.f, re = 0.f;
            if (br == 1) {   // x runs 0..127; 8-run may need out-of-run edge values
                if (offA >= 0 && offA <= 508 && (u0 & 127) != 0)   le = bf2f(vp[offA - 1]);
                if (offB >= 0 && offB <= 508 && (u0 & 127) != 120) re = bf2f(vp[offB + 4]);
            }
            float w0 = wp[(r + 1) * 3 + 0], w1 = wp[(r + 1) * 3 + 1], w2 = wp[(r + 1) * 3 + 2];
            #pragma unroll
            for (int j = 0; j < 8; ++j) {
                float lv, rv2;
                if (j == 0) lv = (br == 0) ? 0.f : le;
                else        lv = (br == 0 && (j & 3) == 0) ? 0.f : m[j - 1];
                if (j == 7) rv2 = (br == 0) ? 0.f : re;
                else        rv2 = (br == 0 && (j & 3) == 3) ? 0.f : m[j + 1];
                acc[j] += w0 * lv + w1 * m[j] + w2 * rv2;
            }
        }
        int cdp = cd ^ (((u0 >> 3) & 7) << 3);   // XOR swizzle for phase-2 bank spread
        #pragma unroll
        for (int j = 0; j < 8; ++j)
            o_s[(u0 + j) * 72 + cdp] = f2bf(acc[j]);
    }
    __syncthreads();
    // ---- phase 2: coalesced RMW (8 lanes cover 128B per token)
    for (int i = 0; i < 8; ++i) {
        int c = i * 512 + tid;
        int tok = c >> 3, cg = c & 7;
        int cgp = cg ^ ((tok >> 3) & 7);
        uint4 lv = *(const uint4*)&o_s[tok * 72 + cgp * 8];
        u16 lh[8]; *(uint4*)lh = lv;
        u16* p = &xcb[(size_t)(wbase + tok) * stride + hh * 64 + cg * 8];
        uint4 gv = *(const uint4*)p;
        u16 gh[8]; *(uint4*)gh = gv;
        u16 oh[8] __attribute__((aligned(16)));
        #pragma unroll
        for (int j = 0; j < 8; ++j) oh[j] = f2bf(bf2f(gh[j]) + bf2f(lh[j]));
        *(uint4*)p = *(const uint4*)oh;
    }
}

// ---------------- K4: proj GEMM (global_load_lds + dbuf) -> out fp32 [B][C][H][W] ----------------
__global__ __launch_bounds__(256) void proj_kernel(const u16* __restrict__ pwc,
        const u16* __restrict__ xc0, const u16* __restrict__ xnov,
        const float* __restrict__ pb, float* __restrict__ out) {
    __shared__ __align__(16) u16 a_tile[2][128 * 32];
    __shared__ __align__(16) u16 b_tile[2][128 * 32];
    int m0 = blockIdx.y * 128, n0 = blockIdx.x * 128;
    int tid = threadIdx.x;
    int lane = tid & 63, wid = tid >> 6;
    int wm = wid >> 1, wn = wid & 1;
    int l15 = lane & 15, quad = lane >> 4;
    int srow = tid >> 2, sgg = tid & 3;
    const u16* gA0 = pwc + (size_t)(m0 + srow) * 256 + sgg * 8;
    const u16* gA1 = gA0 + (size_t)64 * 256;
    const u16* gB0lo = xc0 + (size_t)t2u0(n0 + srow) * 128 + sgg * 8;
    const u16* gB1lo = xc0 + (size_t)t2u0(n0 + srow + 64) * 128 + sgg * 8;
    const u16* gB0hi = xnov + (size_t)(n0 + srow) * 256 + sgg * 8;       // + k0 (>=128) directly
    const u16* gB1hi = xnov + (size_t)(n0 + srow + 64) * 256 + sgg * 8;
    int lb0 = wid * 1024, lb1 = 4096 + wid * 1024;
    gl_lds16(gA0, (u16*)((char*)&a_tile[0][0] + lb0));
    gl_lds16(gA1, (u16*)((char*)&a_tile[0][0] + lb1));
    gl_lds16(gB0lo, (u16*)((char*)&b_tile[0][0] + lb0));
    gl_lds16(gB1lo, (u16*)((char*)&b_tile[0][0] + lb1));
    f32x4 acc[4][4] = {};
    for (int ks = 0; ks < 8; ++ks) {
        __syncthreads();
        int cur = ks & 1;
        if (ks < 7) {
            int k0 = (ks + 1) * 32;
            int nb = cur ^ 1;
            gl_lds16(gA0 + k0, (u16*)((char*)&a_tile[nb][0] + lb0));
            gl_lds16(gA1 + k0, (u16*)((char*)&a_tile[nb][0] + lb1));
            const u16* b0 = (k0 < 128) ? (gB0lo + k0) : (gB0hi + k0);
            const u16* b1 = (k0 < 128) ? (gB1lo + k0) : (gB1hi + k0);
            gl_lds16(b0, (u16*)((char*)&b_tile[nb][0] + lb0));
            gl_lds16(b1, (u16*)((char*)&b_tile[nb][0] + lb1));
        }
        bf16x8v af[4], bf[4];
        #pragma unroll
        for (int i = 0; i < 4; ++i) {
            af[i] = *(const bf16x8v*)&a_tile[cur][(wm * 64 + i * 16 + l15) * 32 + quad * 8];
            bf[i] = *(const bf16x8v*)&b_tile[cur][(wn * 64 + i * 16 + l15) * 32 + quad * 8];
        }
        #pragma unroll
        for (int i = 0; i < 4; ++i)
            #pragma unroll
            for (int j = 0; j < 4; ++j)
                acc[i][j] = mfma_b(af[i], bf[j], acc[i][j]);
    }
    #pragma unroll
    for (int i = 0; i < 4; ++i) {
        int mbase = m0 + wm * 64 + i * 16 + quad * 4;
        #pragma unroll
        for (int j = 0; j < 4; ++j) {
            int nc = n0 + wn * 64 + j * 16 + l15;
            #pragma unroll
            for (int r = 0; r < 4; ++r) {
                int m = mbase + r;
                out[((size_t)(nc >> 14) * 256 + m) * HW_ + (nc & 16383)] = acc[i][j][r] + pb[m];
            }
        }
    }
}

extern "C" void kernel_launch(void* const* d_in, const int* in_sizes, int n_in,
                              void* d_out, int out_size, void* d_ws, size_t ws_size,
                              hipStream_t stream) {
    const float* x     = (const float*)d_in[0];
    const float* ln_g  = (const float*)d_in[1];
    const float* ln_b  = (const float*)d_in[2];
    const float* w_qkv = (const float*)d_in[3];
    const float* lw1   = (const float*)d_in[4];
    const float* lb1   = (const float*)d_in[5];
    const float* lw2   = (const float*)d_in[6];
    const float* lb2   = (const float*)d_in[7];
    const float* pw    = (const float*)d_in[8];
    const float* pb    = (const float*)d_in[9];
    float* out = (float*)d_out;
    u16* out_u16 = (u16*)d_out;          // 64 MiB scratch during pipeline
    char* ws = (char*)d_ws;

    if (ws_size < 67108864) {
        sentinel_kernel<<<dim3(1), dim3(64), 0, stream>>>(out, 1.0e6f + (float)(ws_size >> 20));
        return;
    }

    u16* xn  = (u16*)ws;                 // 32 MiB; rows' 2nd halves become xc1 overlay
    u16* xc0 = (u16*)(ws + 33554432);    // 16 MiB xc0 (br0 u-order, stride 128) - survives to proj
    u16* wtf = (u16*)(ws + 50331648);    // 768 KiB fragment-ordered bf16 w_qkv
    u16* pwc = wtf + 393216;             // 128 KiB bf16 k-permuted proj weights
    u16* vpl = out_u16;                  // 16 MiB V planes (per branch, reused)
    u16* qkt = out_u16 + 8388608;        // 32 MiB Q/K token-major (per branch, reused)

    wconv_kernel<<<dim3(96), dim3(256), 0, stream>>>(w_qkv, pw, wtf, pwc);
    ln_kernel<<<dim3(256), dim3(512), 0, stream>>>(x, ln_g, ln_b, xn);
    // branch 0
    qkv_gemm<<<dim3(512), dim3(256), 0, stream>>>(wtf, xn, qkt, vpl, 0);
    attn_kernel<<<dim3(1024), dim3(512), 0, stream>>>(qkt, vpl, xc0, 128);
    lepe_kernel<<<dim3(256), dim3(512), 0, stream>>>(vpl, lw1, lb1, xc0, 128, 0);
    // branch 1
    qkv_gemm<<<dim3(512), dim3(256), 0, stream>>>(wtf, xn, qkt, vpl, 1);
    attn_kernel<<<dim3(1024), dim3(512), 0, stream>>>(qkt, vpl, xn + 128, 256);
    lepe_kernel<<<dim3(256), dim3(512), 0, stream>>>(vpl, lw2, lb2, xn + 128, 256, 1);
    // proj reads xc0 from ws (no copy needed; d_out fully free for fp32 output)
    proj_kernel<<<dim3(512, 2), dim3(256), 0, stream>>>(pwc, xc0, xn, pb, out);
}

// Round 12
// 353.671 us; speedup vs baseline: 1.1767x; 1.1767x over previous
//
#include <hip/hip_runtime.h>
#include <stdint.h>

#define T_ 65536
#define HW_ 16384
#define SCALE_F 0.08838834764831845f
#define EPS_ 1e-4f

typedef unsigned short u16;
typedef unsigned int u32;
typedef __attribute__((ext_vector_type(4))) float f32x4;
typedef __attribute__((ext_vector_type(8))) __bf16 bf16x8v;

union frag_u { u16 h[8]; bf16x8v v; uint4 q4; };

__device__ __forceinline__ float bf2f(u16 h) {
    union { u32 u; float f; } x; x.u = ((u32)h) << 16; return x.f;
}
__device__ __forceinline__ u16 f2bf(float f) {
    union { u32 u; float f; } x; x.f = f;
    u32 u = x.u;
    return (u16)((u + 0x7FFFu + ((u >> 16) & 1u)) >> 16);
}
__device__ __forceinline__ f32x4 mfma_b(bf16x8v a, bf16x8v b, f32x4 c) {
    return __builtin_amdgcn_mfma_f32_16x16x32_bf16(a, b, c, 0, 0, 0);
}
// async global->LDS 16B: lds dest = wave-uniform base + lane*16
__device__ __forceinline__ void gl_lds16(const u16* g, u16* l) {
    __builtin_amdgcn_global_load_lds(
        (const __attribute__((address_space(1))) void*)g,
        (__attribute__((address_space(3))) void*)l, 16, 0, 0);
}

// window-major token u -> global token t (br0: vertical strips 128x4)
__device__ __forceinline__ int u2t(int u, int br) {
    if (br == 1) return u;
    int b = u >> 14, rr = u & 16383;
    int s = rr >> 9, rem = rr & 511;
    int y = rem >> 2, xl = rem & 3;
    return (b << 14) + (y << 7) + (s << 2) + xl;
}
// global token t -> br0 window-major u
__device__ __forceinline__ int t2u0(int t) {
    int b = t >> 14, rr = t & 16383;
    int y = rr >> 7, x = rr & 127;
    return (b << 14) + ((x >> 2) << 9) + (y << 2) + (x & 3);
}

__global__ void sentinel_kernel(float* out, float code) {
    if (blockIdx.x == 0 && threadIdx.x == 0) out[0] = code;
}

// ---------------- K0: weight pre-convert ----------------
// blocks [0,64): w_qkv -> wtf, fragment-ordered bf16:
//   chunk id = ((((my*2+br)*2+wm)*8+ks)*4+i)*64 + lane  (16B each)
//   my<2 (Q,K): fragment position p = wm*64+i*16+(lane&15) holds SOURCE col
//     c = ((p&63)<<1)|(p>>6)  (de-interleave perm baked in, so qkv stores col=p directly)
//   my=2 (V): direct mapping c = p.
// blocks [64,96): pw -> pwc bf16, k-permutation baked in
__global__ __launch_bounds__(256) void wconv_kernel(const float* __restrict__ w,
        const float* __restrict__ pw, u16* __restrict__ wtf, u16* __restrict__ pwc) {
    int bid = blockIdx.x;
    int tid = threadIdx.x;
    if (bid < 64) {
        for (int it = 0; it < 3; ++it) {
            int id = (bid * 3 + it) * 256 + tid;   // 49152 chunks
            int lane = id & 63;
            int i  = (id >> 6) & 3;
            int ks = (id >> 8) & 7;
            int wm = (id >> 11) & 1;
            int br = (id >> 12) & 1;
            int my = id >> 13;
            int p = wm * 64 + i * 16 + (lane & 15);
            int srccol = (my < 2) ? (((p & 63) << 1) | (p >> 6)) : p;
            int col = my * 256 + br * 128 + srccol;
            int k0 = ks * 32 + ((lane >> 4) & 3) * 8;
            u16 tmp[8] __attribute__((aligned(16)));
            #pragma unroll
            for (int e = 0; e < 8; ++e)
                tmp[e] = f2bf(w[(size_t)(k0 + e) * 768 + col]);
            *(uint4*)&wtf[(size_t)id * 8] = *(const uint4*)tmp;
        }
    } else {
        int base = (bid - 64) * 2048;
        for (int i = 0; i < 8; ++i) {
            int e = base + i * 256 + tid;
            int m = e >> 8, ks = e & 255;
            int c = (ks < 128) ? (2 * (ks & 63) + (ks >> 6))
                               : (128 + 2 * ((ks - 128) & 63) + ((ks - 128) >> 6));
            pwc[e] = f2bf(pw[(size_t)m * 256 + c]);
        }
    }
}

// ---------------- K1: LayerNorm over C, burst-contiguous reads ----------------
__global__ __launch_bounds__(512, 2) void ln_kernel(const float* __restrict__ x,
        const float* __restrict__ g, const float* __restrict__ bta, u16* __restrict__ xn) {
    __shared__ float reds[8][260];
    __shared__ float redss[8][260];
    __shared__ float mus[256];
    __shared__ float rstds[256];
    int tid = threadIdx.x, lane = tid & 63, w = tid >> 6;
    int w32 = w * 32;
    int tok0 = blockIdx.x * 256 + lane * 4;
    int b = tok0 >> 14, hw = tok0 & 16383;
    const float* xb = x + (size_t)b * 256 * HW_ + hw;
    float4 v[32];
    #pragma unroll
    for (int j = 0; j < 32; ++j)
        v[j] = *(const float4*)(xb + (size_t)(w32 + j) * HW_);
    float s0 = 0.f, s1 = 0.f, s2 = 0.f, s3 = 0.f;
    float q0 = 0.f, q1 = 0.f, q2 = 0.f, q3 = 0.f;
    #pragma unroll
    for (int j = 0; j < 32; ++j) {
        s0 += v[j].x; q0 += v[j].x * v[j].x;
        s1 += v[j].y; q1 += v[j].y * v[j].y;
        s2 += v[j].z; q2 += v[j].z * v[j].z;
        s3 += v[j].w; q3 += v[j].w * v[j].w;
    }
    *(float4*)&reds[w][lane * 4]  = make_float4(s0, s1, s2, s3);
    *(float4*)&redss[w][lane * 4] = make_float4(q0, q1, q2, q3);
    __syncthreads();
    if (tid < 256) {
        float S = 0.f, SS = 0.f;
        #pragma unroll
        for (int p = 0; p < 8; ++p) { S += reds[p][tid]; SS += redss[p][tid]; }
        float mu = S * (1.f / 256.f);
        float var = SS * (1.f / 256.f) - mu * mu;
        mus[tid] = mu;
        rstds[tid] = rsqrtf(var + EPS_);
    }
    __syncthreads();
    float4 mu4 = *(const float4*)&mus[lane * 4];
    float4 rs4 = *(const float4*)&rstds[lane * 4];
    float mk[4] = {mu4.x, mu4.y, mu4.z, mu4.w};
    float rk[4] = {rs4.x, rs4.y, rs4.z, rs4.w};
    #pragma unroll
    for (int k = 0; k < 4; ++k) {
        u16 tmp[32] __attribute__((aligned(16)));
        #pragma unroll
        for (int j = 0; j < 32; ++j) {
            int c = w32 + j;
            float xv = (k == 0) ? v[j].x : (k == 1) ? v[j].y : (k == 2) ? v[j].z : v[j].w;
            tmp[j] = f2bf((xv - mk[k]) * rk[k] * g[c] + bta[c]);
        }
        u16* o = xn + (size_t)(tok0 + k) * 256 + w32;
        *(uint4*)(o)      = *(const uint4*)&tmp[0];
        *(uint4*)(o + 8)  = *(const uint4*)&tmp[8];
        *(uint4*)(o + 16) = *(const uint4*)&tmp[16];
        *(uint4*)(o + 24) = *(const uint4*)&tmp[24];
    }
}

// ---------------- K2: merged Q/K/V GEMM ----------------
// B staged once (full K, 64KB, burst gload_lds, XOR-swizzled via pre-swizzled source).
// Q/K passes compute the TRANSPOSED product (mfma(bf,af)) so the C-fragment's l15 dim
// lands on the output column -> 32B-contiguous stores (fixes 2B-scatter epilogue).
__global__ __launch_bounds__(256) void qkv_gemm(const u16* __restrict__ wtf,
        const u16* __restrict__ xn, u16* __restrict__ qkt, u16* __restrict__ vpl, int br) {
    __shared__ __align__(16) u16 b_lds[128 * 256];   // 64 KB
    int n0 = blockIdx.x * 128;
    int tid = threadIdx.x;
    int lane = tid & 63, wid = tid >> 6;
    int wm = wid >> 1, wn = wid & 1;
    int l15 = lane & 15, quad = lane >> 4;
    // ---- stage B: 16 rounds, wave covers 2 full rows (1KB contiguous global)
    {
        int c_lds = lane & 31;           // 16B chunk slot within row
        for (int r = 0; r < 16; ++r) {
            int row = r * 8 + wid * 2 + (lane >> 5);
            int t = u2t(n0 + row, br);
            int cg = c_lds ^ (row & 7);  // inverse-swizzled source chunk
            const u16* gsrc = xn + (size_t)t * 256 + cg * 8;
            u16* ldst = &b_lds[(r * 8 + wid * 2) * 256];   // wave-uniform base
            gl_lds16(gsrc, ldst);
        }
    }
    __syncthreads();   // vmcnt(0) drain: staged B visible
    #pragma unroll 1
    for (int my = 0; my < 3; ++my) {
        const u16* abase = wtf + (size_t)(((my * 2 + br) * 2 + wm) * 8) * 4 * 64 * 8;
        f32x4 acc[4][4] = {};
        #pragma unroll
        for (int ks = 0; ks < 8; ++ks) {
            frag_u af[4];
            bf16x8v bf[4];
            #pragma unroll
            for (int i = 0; i < 4; ++i)
                af[i].q4 = *(const uint4*)&abase[(size_t)(ks * 4 + i) * 512 + lane * 8];
            #pragma unroll
            for (int i = 0; i < 4; ++i) {
                int rowb = wn * 64 + i * 16 + l15;
                int cl2 = (ks * 4 + quad) ^ (rowb & 7);   // swizzled read
                bf[i] = *(const bf16x8v*)&b_lds[rowb * 256 + cl2 * 8];
            }
            if (my < 2) {
                #pragma unroll
                for (int i = 0; i < 4; ++i)
                    #pragma unroll
                    for (int j = 0; j < 4; ++j)
                        acc[i][j] = mfma_b(bf[j], af[i].v, acc[i][j]);   // C^T: l15->col
            } else {
                #pragma unroll
                for (int i = 0; i < 4; ++i)
                    #pragma unroll
                    for (int j = 0; j < 4; ++j)
                        acc[i][j] = mfma_b(af[i].v, bf[j], acc[i][j]);
            }
        }
        if (my < 2) {
            // acc[i][j]: col = cb2+wm*64+i*16+l15 (perm baked in wtf), u = n0+wn*64+j*16+quad*4+r
            int cb2 = my * 128;
            int colw = cb2 + wm * 64 + l15;
            #pragma unroll
            for (int i = 0; i < 4; ++i) {
                #pragma unroll
                for (int j = 0; j < 4; ++j) {
                    #pragma unroll
                    for (int r = 0; r < 4; ++r) {
                        int u = n0 + wn * 64 + j * 16 + quad * 4 + r;
                        qkt[(size_t)u * 256 + colw + i * 16] = f2bf(acc[i][j][r]);
                    }
                }
            }
        } else {
            #pragma unroll
            for (int i = 0; i < 4; ++i) {
                int pbase = wm * 64 + i * 16 + quad * 4;
                #pragma unroll
                for (int j = 0; j < 4; ++j) {
                    int u = n0 + wn * 64 + j * 16 + l15;
                    #pragma unroll
                    for (int r = 0; r < 4; ++r)
                        vpl[(size_t)(pbase + r) * T_ + u] = f2bf(acc[i][j][r]);
                }
            }
        }
    }
}

// ---------------- K3: attention, flash-style online softmax; 70KB LDS -> 2 blocks/CU ----
__global__ __launch_bounds__(512, 4) void attn_kernel(const u16* __restrict__ qkt,
        const u16* __restrict__ vpl, u16* __restrict__ xcb, int stride) {
    __shared__ __align__(16) u16 k_area[2][128 * 72];   // 36864 B
    __shared__ __align__(16) u16 v_lds[2][64 * 136];    // 34816 B
    int bid = blockIdx.x;
    int id2 = (bid & 7) * 128 + (bid >> 3);   // XCD swizzle: one window's 8 blocks share an XCD
    int window = id2 >> 3, h = (id2 >> 2) & 1, qq = id2 & 3;
    int wbase = window * 512;
    int tid = threadIdx.x, lane = tid & 63, wid = tid >> 6;
    int l15 = lane & 15, quad = lane >> 4;

    // Q A-frags (token-major rows, de-interleaved: cols h*64 + cd)
    frag_u af[2];
    {
        size_t qrow = (size_t)(wbase + qq * 128 + wid * 16 + l15) * 256 + h * 64 + quad * 8;
        af[0].q4 = *(const uint4*)&qkt[qrow];
        af[1].q4 = *(const uint4*)&qkt[qrow + 32];
    }
    // stage K chunk 0 + V chunk 0
    for (int idx = tid; idx < 1024; idx += 512) {
        int tok = idx >> 3, c8 = (idx & 7) * 8;
        *(uint4*)&k_area[0][tok * 72 + c8] =
            *(const uint4*)&qkt[(size_t)(wbase + tok) * 256 + 128 + h * 64 + c8];
    }
    for (int idx = tid; idx < 1024; idx += 512) {
        int cd = idx >> 4, k8 = (idx & 15) * 8;
        *(uint4*)&v_lds[0][cd * 136 + k8] =
            *(const uint4*)&vpl[(size_t)(2 * cd + h) * T_ + wbase + k8];
    }
    __syncthreads();

    float m[4] = {-1e30f, -1e30f, -1e30f, -1e30f};
    float l[4] = {0.f, 0.f, 0.f, 0.f};   // lane-partial; reduced once at the end
    f32x4 acc_o[4] = {};
    for (int ch = 0; ch < 4; ++ch) {
        int cur = ch & 1, nxt = cur ^ 1;
        if (ch < 3) {   // prefetch next K/V chunk into the other buffers
            for (int idx = tid; idx < 1024; idx += 512) {
                int tok = idx >> 3, c8 = (idx & 7) * 8;
                *(uint4*)&k_area[nxt][tok * 72 + c8] =
                    *(const uint4*)&qkt[(size_t)(wbase + (ch + 1) * 128 + tok) * 256 + 128 + h * 64 + c8];
            }
            for (int idx = tid; idx < 1024; idx += 512) {
                int cd = idx >> 4, k8 = (idx & 15) * 8;
                *(uint4*)&v_lds[nxt][cd * 136 + k8] =
                    *(const uint4*)&vpl[(size_t)(2 * cd + h) * T_ + wbase + (ch + 1) * 128 + k8];
            }
        }
        // ---- S chunk = Q.K^T (lane: q-row = quad*4+r, k-col = kt*16+l15)
        f32x4 s[8];
        #pragma unroll
        for (int kt = 0; kt < 8; ++kt) {
            f32x4 z = {0.f, 0.f, 0.f, 0.f};
            bf16x8v b0 = *(const bf16x8v*)&k_area[cur][(kt * 16 + l15) * 72 + quad * 8];
            bf16x8v b1 = *(const bf16x8v*)&k_area[cur][(kt * 16 + l15) * 72 + 32 + quad * 8];
            z = mfma_b(af[0].v, b0, z);
            z = mfma_b(af[1].v, b1, z);
            s[kt] = z;
        }
        // ---- online softmax update
        float cmx[4] = {-1e30f, -1e30f, -1e30f, -1e30f};
        #pragma unroll
        for (int kt = 0; kt < 8; ++kt)
            #pragma unroll
            for (int r = 0; r < 4; ++r) cmx[r] = fmaxf(cmx[r], s[kt][r]);
        #pragma unroll
        for (int d = 1; d < 16; d <<= 1)
            #pragma unroll
            for (int r = 0; r < 4; ++r) cmx[r] = fmaxf(cmx[r], __shfl_xor(cmx[r], d, 16));
        float alpha[4];
        #pragma unroll
        for (int r = 0; r < 4; ++r) {
            float mn = fmaxf(m[r], cmx[r]);
            alpha[r] = __expf((m[r] - mn) * SCALE_F);
            m[r] = mn;
        }
        float ps[4] = {0.f, 0.f, 0.f, 0.f};
        #pragma unroll
        for (int kt = 0; kt < 8; ++kt)
            #pragma unroll
            for (int r = 0; r < 4; ++r) {
                float p = __expf((s[kt][r] - m[r]) * SCALE_F);
                s[kt][r] = p;
                ps[r] += p;
            }
        #pragma unroll
        for (int r = 0; r < 4; ++r) l[r] = l[r] * alpha[r] + ps[r];
        #pragma unroll
        for (int cs = 0; cs < 4; ++cs)
            #pragma unroll
            for (int r = 0; r < 4; ++r) acc_o[cs][r] *= alpha[r];
        __syncthreads();   // all waves done reading k_area[cur] before P overlays it
        // ---- P.V for this chunk (P transposed via wave-private overlay on k_area[cur])
        u16* p_lds = &k_area[cur][wid * 1152];
        #pragma unroll
        for (int half = 0; half < 2; ++half) {
            #pragma unroll
            for (int kt4 = 0; kt4 < 4; ++kt4)
                #pragma unroll
                for (int rr = 0; rr < 4; ++rr)
                    p_lds[(quad * 4 + rr) * 72 + kt4 * 16 + l15] = f2bf(s[half * 4 + kt4][rr]);
            #pragma unroll
            for (int k32 = 0; k32 < 2; ++k32) {
                bf16x8v pa = *(const bf16x8v*)&p_lds[l15 * 72 + k32 * 32 + quad * 8];
                #pragma unroll
                for (int cs = 0; cs < 4; ++cs) {
                    bf16x8v vf = *(const bf16x8v*)&v_lds[cur]
                        [(cs * 16 + l15) * 136 + half * 64 + k32 * 32 + quad * 8];
                    acc_o[cs] = mfma_b(pa, vf, acc_o[cs]);
                }
            }
        }
        __syncthreads();   // prefetch landed; p_lds reads done before next iter's overwrite
    }
    // ---- final: reduce l across the 16-lane row group, normalize, store
    float linv[4];
    #pragma unroll
    for (int r = 0; r < 4; ++r) {
        float v = l[r];
        #pragma unroll
        for (int d = 1; d < 16; d <<= 1) v += __shfl_xor(v, d, 16);
        linv[r] = 1.f / v;
    }
    #pragma unroll
    for (int cs = 0; cs < 4; ++cs) {
        int col = h * 64 + cs * 16 + l15;
        #pragma unroll
        for (int r = 0; r < 4; ++r) {
            int u = wbase + qq * 128 + wid * 16 + quad * 4 + r;
            xcb[(size_t)u * stride + col] = f2bf(acc_o[cs][r] * linv[r]);
        }
    }
}

// ---------------- K3b: LePE depthwise 3x3, window-tiled with LDS transpose ----------------
__global__ __launch_bounds__(512) void lepe_kernel(const u16* __restrict__ vpl,
        const float* __restrict__ lw, const float* __restrict__ lb,
        u16* __restrict__ xcb, int stride, int br) {
    __shared__ __align__(16) u16 o_s[512 * 72];   // 73728 B, rows 16B-aligned
    int hh = blockIdx.x & 1, wdw = blockIdx.x >> 1;
    int wbase = wdw * 512;
    int tid = threadIdx.x;
    int xd = (br == 0) ? 4 : 128;   // y-step in u-space (window image: br0 128x4, br1 4x128)
    // ---- phase 1: conv; thread group g covers (cd, 8-token run)
    for (int i = 0; i < 8; ++i) {
        int g = i * 512 + tid;
        int cd = g >> 6, u0 = (g & 63) * 8;
        int cl = 2 * cd + hh;
        const u16* vp = vpl + (size_t)cl * T_ + wbase;
        const float* wp = lw + cl * 9;
        float bias = lb[cl];
        float acc[8];
        #pragma unroll
        for (int j = 0; j < 8; ++j) acc[j] = bias;
        #pragma unroll
        for (int r = -1; r <= 1; ++r) {
            int offA = u0 + r * xd;     // y-tap validity: tok+r*xd in [0,512)
            int offB = offA + 4;
            float m[8];
            if (offA >= 0 && offA <= 508) {
                uint2 va = *(const uint2*)&vp[offA];
                u16 ha[4]; *(uint2*)ha = va;
                #pragma unroll
                for (int j = 0; j < 4; ++j) m[j] = bf2f(ha[j]);
            } else { m[0] = m[1] = m[2] = m[3] = 0.f; }
            if (offB >= 0 && offB <= 508) {
                uint2 vb = *(const uint2*)&vp[offB];
                u16 hb[4]; *(uint2*)hb = vb;
                #pragma unroll
                for (int j = 0; j < 4; ++j) m[4 + j] = bf2f(hb[j]);
            } else { m[4] = m[5] = m[6] = m[7] = 0.f; }
            float le = 0.f, re = 0.f;
            if (br == 1) {   // x runs 0..127; 8-run may need out-of-run edge values
                if (offA >= 0 && offA <= 508 && (u0 & 127) != 0)   le = bf2f(vp[offA - 1]);
                if (offB >= 0 && offB <= 508 && (u0 & 127) != 120) re = bf2f(vp[offB + 4]);
            }
            float w0 = wp[(r + 1) * 3 + 0], w1 = wp[(r + 1) * 3 + 1], w2 = wp[(r + 1) * 3 + 2];
            #pragma unroll
            for (int j = 0; j < 8; ++j) {
                float lv, rv2;
                if (j == 0) lv = (br == 0) ? 0.f : le;
                else        lv = (br == 0 && (j & 3) == 0) ? 0.f : m[j - 1];
                if (j == 7) rv2 = (br == 0) ? 0.f : re;
                else        rv2 = (br == 0 && (j & 3) == 3) ? 0.f : m[j + 1];
                acc[j] += w0 * lv + w1 * m[j] + w2 * rv2;
            }
        }
        int cdp = cd ^ (((u0 >> 3) & 7) << 3);   // XOR swizzle for phase-2 bank spread
        #pragma unroll
        for (int j = 0; j < 8; ++j)
            o_s[(u0 + j) * 72 + cdp] = f2bf(acc[j]);
    }
    __syncthreads();
    // ---- phase 2: coalesced RMW (8 lanes cover 128B per token)
    for (int i = 0; i < 8; ++i) {
        int c = i * 512 + tid;
        int tok = c >> 3, cg = c & 7;
        int cgp = cg ^ ((tok >> 3) & 7);
        uint4 lv = *(const uint4*)&o_s[tok * 72 + cgp * 8];
        u16 lh[8]; *(uint4*)lh = lv;
        u16* p = &xcb[(size_t)(wbase + tok) * stride + hh * 64 + cg * 8];
        uint4 gv = *(const uint4*)p;
        u16 gh[8]; *(uint4*)gh = gv;
        u16 oh[8] __attribute__((aligned(16)));
        #pragma unroll
        for (int j = 0; j < 8; ++j) oh[j] = f2bf(bf2f(gh[j]) + bf2f(lh[j]));
        *(uint4*)p = *(const uint4*)oh;
    }
}

// ---------------- K4: proj GEMM (global_load_lds + dbuf) -> out fp32 [B][C][H][W] ----------------
__global__ __launch_bounds__(256) void proj_kernel(const u16* __restrict__ pwc,
        const u16* __restrict__ xc0, const u16* __restrict__ xnov,
        const float* __restrict__ pb, float* __restrict__ out) {
    __shared__ __align__(16) u16 a_tile[2][128 * 32];
    __shared__ __align__(16) u16 b_tile[2][128 * 32];
    int m0 = blockIdx.y * 128, n0 = blockIdx.x * 128;
    int tid = threadIdx.x;
    int lane = tid & 63, wid = tid >> 6;
    int wm = wid >> 1, wn = wid & 1;
    int l15 = lane & 15, quad = lane >> 4;
    int srow = tid >> 2, sgg = tid & 3;
    const u16* gA0 = pwc + (size_t)(m0 + srow) * 256 + sgg * 8;
    const u16* gA1 = gA0 + (size_t)64 * 256;
    const u16* gB0lo = xc0 + (size_t)t2u0(n0 + srow) * 128 + sgg * 8;
    const u16* gB1lo = xc0 + (size_t)t2u0(n0 + srow + 64) * 128 + sgg * 8;
    const u16* gB0hi = xnov + (size_t)(n0 + srow) * 256 + sgg * 8;       // + k0 (>=128) directly
    const u16* gB1hi = xnov + (size_t)(n0 + srow + 64) * 256 + sgg * 8;
    int lb0 = wid * 1024, lb1 = 4096 + wid * 1024;
    gl_lds16(gA0, (u16*)((char*)&a_tile[0][0] + lb0));
    gl_lds16(gA1, (u16*)((char*)&a_tile[0][0] + lb1));
    gl_lds16(gB0lo, (u16*)((char*)&b_tile[0][0] + lb0));
    gl_lds16(gB1lo, (u16*)((char*)&b_tile[0][0] + lb1));
    f32x4 acc[4][4] = {};
    for (int ks = 0; ks < 8; ++ks) {
        __syncthreads();
        int cur = ks & 1;
        if (ks < 7) {
            int k0 = (ks + 1) * 32;
            int nb = cur ^ 1;
            gl_lds16(gA0 + k0, (u16*)((char*)&a_tile[nb][0] + lb0));
            gl_lds16(gA1 + k0, (u16*)((char*)&a_tile[nb][0] + lb1));
            const u16* b0 = (k0 < 128) ? (gB0lo + k0) : (gB0hi + k0);
            const u16* b1 = (k0 < 128) ? (gB1lo + k0) : (gB1hi + k0);
            gl_lds16(b0, (u16*)((char*)&b_tile[nb][0] + lb0));
            gl_lds16(b1, (u16*)((char*)&b_tile[nb][0] + lb1));
        }
        bf16x8v af[4], bf[4];
        #pragma unroll
        for (int i = 0; i < 4; ++i) {
            af[i] = *(const bf16x8v*)&a_tile[cur][(wm * 64 + i * 16 + l15) * 32 + quad * 8];
            bf[i] = *(const bf16x8v*)&b_tile[cur][(wn * 64 + i * 16 + l15) * 32 + quad * 8];
        }
        #pragma unroll
        for (int i = 0; i < 4; ++i)
            #pragma unroll
            for (int j = 0; j < 4; ++j)
                acc[i][j] = mfma_b(af[i], bf[j], acc[i][j]);
    }
    #pragma unroll
    for (int i = 0; i < 4; ++i) {
        int mbase = m0 + wm * 64 + i * 16 + quad * 4;
        #pragma unroll
        for (int j = 0; j < 4; ++j) {
            int nc = n0 + wn * 64 + j * 16 + l15;
            #pragma unroll
            for (int r = 0; r < 4; ++r) {
                int m = mbase + r;
                out[((size_t)(nc >> 14) * 256 + m) * HW_ + (nc & 16383)] = acc[i][j][r] + pb[m];
            }
        }
    }
}

extern "C" void kernel_launch(void* const* d_in, const int* in_sizes, int n_in,
                              void* d_out, int out_size, void* d_ws, size_t ws_size,
                              hipStream_t stream) {
    const float* x     = (const float*)d_in[0];
    const float* ln_g  = (const float*)d_in[1];
    const float* ln_b  = (const float*)d_in[2];
    const float* w_qkv = (const float*)d_in[3];
    const float* lw1   = (const float*)d_in[4];
    const float* lb1   = (const float*)d_in[5];
    const float* lw2   = (const float*)d_in[6];
    const float* lb2   = (const float*)d_in[7];
    const float* pw    = (const float*)d_in[8];
    const float* pb    = (const float*)d_in[9];
    float* out = (float*)d_out;
    u16* out_u16 = (u16*)d_out;          // 64 MiB scratch during pipeline
    char* ws = (char*)d_ws;

    if (ws_size < 67108864) {
        sentinel_kernel<<<dim3(1), dim3(64), 0, stream>>>(out, 1.0e6f + (float)(ws_size >> 20));
        return;
    }

    u16* xn  = (u16*)ws;                 // 32 MiB; rows' 2nd halves become xc1 overlay
    u16* xc0 = (u16*)(ws + 33554432);    // 16 MiB xc0 (br0 u-order, stride 128) - survives to proj
    u16* wtf = (u16*)(ws + 50331648);    // 768 KiB fragment-ordered bf16 w_qkv
    u16* pwc = wtf + 393216;             // 128 KiB bf16 k-permuted proj weights
    u16* vpl = out_u16;                  // 16 MiB V planes (per branch, reused)
    u16* qkt = out_u16 + 8388608;        // 32 MiB Q/K token-major (per branch, reused)

    wconv_kernel<<<dim3(96), dim3(256), 0, stream>>>(w_qkv, pw, wtf, pwc);
    ln_kernel<<<dim3(256), dim3(512), 0, stream>>>(x, ln_g, ln_b, xn);
    // branch 0
    qkv_gemm<<<dim3(512), dim3(256), 0, stream>>>(wtf, xn, qkt, vpl, 0);
    attn_kernel<<<dim3(1024), dim3(512), 0, stream>>>(qkt, vpl, xc0, 128);
    lepe_kernel<<<dim3(256), dim3(512), 0, stream>>>(vpl, lw1, lb1, xc0, 128, 0);
    // branch 1
    qkv_gemm<<<dim3(512), dim3(256), 0, stream>>>(wtf, xn, qkt, vpl, 1);
    attn_kernel<<<dim3(1024), dim3(512), 0, stream>>>(qkt, vpl, xn + 128, 256);
    lepe_kernel<<<dim3(256), dim3(512), 0, stream>>>(vpl, lw2, lb2, xn + 128, 256, 1);
    // proj reads xc0 from ws (no copy needed; d_out fully free for fp32 output)
    proj_kernel<<<dim3(512, 2), dim3(256), 0, stream>>>(pwc, xc0, xn, pb, out);
}